// Round 5
// baseline (169.317 us; speedup 1.0000x reference)
//
#include <hip/hip_runtime.h>
#include <math.h>

#define CC 512
#define CB 128
#define BB 32
#define HW 4096
#define NROW (BB * CC)                       // 16384 rows of 4096 floats
#define COPY_BYTES ((size_t)NROW * HW * 2)   // 128 MiB bf16 shadow copy

typedef float f32x4 __attribute__((ext_vector_type(4)));
typedef unsigned short u16x4 __attribute__((ext_vector_type(4)));
typedef unsigned short u16x8 __attribute__((ext_vector_type(8)));

static __device__ __forceinline__ unsigned short f2bf(float x) {
    unsigned u = __float_as_uint(x);
    unsigned r = (u + 0x7fffu + ((u >> 16) & 1u)) >> 16;   // RNE
    return (unsigned short)r;
}
static __device__ __forceinline__ float bf2f(unsigned short b) {
    return __uint_as_float(((unsigned)b) << 16);
}

// ---- kernel 1 (copy path): pool + write bf16 shadow copy ----
// NT loads: input is cold and we do NOT want it claiming L3 — the copy should.
__global__ __launch_bounds__(256) void se_pool_copy(const float* __restrict__ in,
                                                    float* __restrict__ s,
                                                    unsigned short* __restrict__ cp) {
    int bc = blockIdx.x;
    const f32x4* row = (const f32x4*)(in + (size_t)bc * HW);
    u16x4* crow = (u16x4*)(cp + (size_t)bc * HW);
    int t = threadIdx.x;
    float acc = 0.f;
#pragma unroll
    for (int i = 0; i < 4; ++i) {
        f32x4 v = __builtin_nontemporal_load(&row[t + i * 256]);
        acc += v.x + v.y + v.z + v.w;
        u16x4 c;
        c.x = f2bf(v.x); c.y = f2bf(v.y); c.z = f2bf(v.z); c.w = f2bf(v.w);
        crow[t + i * 256] = c;   // normal store -> cache the copy
    }
#pragma unroll
    for (int off = 32; off >= 1; off >>= 1)
        acc += __shfl_xor(acc, off, 64);
    __shared__ float red[4];
    if ((t & 63) == 0) red[t >> 6] = acc;
    __syncthreads();
    if (t == 0) s[bc] = (red[0] + red[1] + red[2] + red[3]) * (1.0f / HW);
}

// ---- kernel 1 (fallback): plain pool ----
__global__ __launch_bounds__(256) void se_pool(const float* __restrict__ in,
                                               float* __restrict__ s) {
    int bc = blockIdx.x;
    const f32x4* row = (const f32x4*)(in + (size_t)bc * HW);
    int t = threadIdx.x;
    float acc = 0.f;
#pragma unroll
    for (int i = 0; i < 4; ++i) {
        f32x4 v = row[t + i * 256];
        acc += v.x + v.y + v.z + v.w;
    }
#pragma unroll
    for (int off = 32; off >= 1; off >>= 1)
        acc += __shfl_xor(acc, off, 64);
    __shared__ float red[4];
    if ((t & 63) == 0) red[t >> 6] = acc;
    __syncthreads();
    if (t == 0) s[bc] = (red[0] + red[1] + red[2] + red[3]) * (1.0f / HW);
}

// ---- kernel 2: h[b][k] = relu(s[b,:] . w1[k,:] + b1[k]) ; one block per k ----
__global__ __launch_bounds__(256) void se_h(const float* __restrict__ s,
                                            const float* __restrict__ w1,
                                            const float* __restrict__ b1,
                                            float* __restrict__ h) {
    int k = blockIdx.x;
    __shared__ float wrow[CC];
    int t = threadIdx.x;
    wrow[t]       = w1[k * CC + t];
    wrow[t + 256] = w1[k * CC + t + 256];
    __syncthreads();
    int b = t >> 3;
    int p = t & 7;
    const float* srow = s + b * CC + p * 64;
    const float* wp   = wrow + p * 64;
    float acc = 0.f;
#pragma unroll
    for (int j = 0; j < 64; ++j) acc += srow[j] * wp[j];
    acc += __shfl_xor(acc, 1, 64);
    acc += __shfl_xor(acc, 2, 64);
    acc += __shfl_xor(acc, 4, 64);
    if (p == 0) {
        float v = acc + b1[k];
        h[b * CB + k] = v > 0.f ? v : 0.f;
    }
}

// ---- kernel 3: batchnorm over batch dim (training-mode biased var), in place ----
__global__ __launch_bounds__(128) void se_bn(float* __restrict__ h,
                                             const float* __restrict__ gamma,
                                             const float* __restrict__ beta) {
    int k = threadIdx.x;
    float sum = 0.f, sumsq = 0.f;
#pragma unroll
    for (int b = 0; b < BB; ++b) {
        float v = h[b * CB + k];
        sum += v;
        sumsq += v * v;
    }
    float mu  = sum * (1.0f / BB);
    float var = sumsq * (1.0f / BB) - mu * mu;
    float sc  = gamma[k] * rsqrtf(var + 1e-5f);
    float sh  = beta[k] - mu * sc;
#pragma unroll
    for (int b = 0; b < BB; ++b)
        h[b * CB + k] = h[b * CB + k] * sc + sh;
}

// ---- kernel 4 (copy path): excite from the bf16 copy ----
__global__ __launch_bounds__(256) void se_mul_bf(const unsigned short* __restrict__ cp,
                                                 const float* __restrict__ hn,
                                                 const float* __restrict__ w2,
                                                 const float* __restrict__ b2,
                                                 float* __restrict__ out) {
    int bc = (NROW - 1) - blockIdx.x;   // recency-aligned: copy tail first
    int b = bc >> 9;
    int c = bc & 511;
    const f32x4* hv = (const f32x4*)(hn + b * CB);
    const f32x4* wv = (const f32x4*)(w2 + c * CB);
    float acc = 0.f;
#pragma unroll
    for (int i = 0; i < 32; ++i) {
        f32x4 a = hv[i];
        f32x4 w = wv[i];
        acc += a.x * w.x + a.y * w.y + a.z * w.z + a.w * w.w;
    }
    float g = 1.0f / (1.0f + expf(-(acc + b2[c])));

    const u16x8* cv = (const u16x8*)(cp + (size_t)bc * HW);
    f32x4* ov       = (f32x4*)(out + (size_t)bc * HW);
    int t = threadIdx.x;
#pragma unroll
    for (int i = 0; i < 2; ++i) {
        u16x8 u = cv[t + i * 256];          // 16B coalesced load of 8 bf16
        f32x4 a, w;
        a.x = bf2f(u[0]) * g; a.y = bf2f(u[1]) * g;
        a.z = bf2f(u[2]) * g; a.w = bf2f(u[3]) * g;
        w.x = bf2f(u[4]) * g; w.y = bf2f(u[5]) * g;
        w.z = bf2f(u[6]) * g; w.w = bf2f(u[7]) * g;
        __builtin_nontemporal_store(a, &ov[(t + i * 256) * 2]);
        __builtin_nontemporal_store(w, &ov[(t + i * 256) * 2 + 1]);
    }
}

// ---- kernel 4 (fallback): R3 version, fp32 re-read ----
__global__ __launch_bounds__(256) void se_mul(const float* __restrict__ in,
                                              const float* __restrict__ hn,
                                              const float* __restrict__ w2,
                                              const float* __restrict__ b2,
                                              float* __restrict__ out) {
    int bc = (NROW - 1) - blockIdx.x;
    int b = bc >> 9;
    int c = bc & 511;
    const f32x4* hv = (const f32x4*)(hn + b * CB);
    const f32x4* wv = (const f32x4*)(w2 + c * CB);
    float acc = 0.f;
#pragma unroll
    for (int i = 0; i < 32; ++i) {
        f32x4 a = hv[i];
        f32x4 w = wv[i];
        acc += a.x * w.x + a.y * w.y + a.z * w.z + a.w * w.w;
    }
    float g = 1.0f / (1.0f + expf(-(acc + b2[c])));

    const f32x4* iv = (const f32x4*)(in + (size_t)bc * HW);
    f32x4* ov       = (f32x4*)(out + (size_t)bc * HW);
    int t = threadIdx.x;
#pragma unroll
    for (int i = 0; i < 4; ++i) {
        f32x4 v = iv[t + i * 256];
        v.x *= g; v.y *= g; v.z *= g; v.w *= g;
        __builtin_nontemporal_store(v, &ov[t + i * 256]);
    }
}

extern "C" void kernel_launch(void* const* d_in, const int* in_sizes, int n_in,
                              void* d_out, int out_size, void* d_ws, size_t ws_size,
                              hipStream_t stream) {
    const float* in    = (const float*)d_in[0];
    const float* w1    = (const float*)d_in[1];
    const float* b1    = (const float*)d_in[2];
    const float* gamma = (const float*)d_in[3];
    const float* beta  = (const float*)d_in[4];
    const float* w2    = (const float*)d_in[5];
    const float* b2    = (const float*)d_in[6];
    float* out = (float*)d_out;

    const size_t small_floats = (size_t)BB * CC + (size_t)BB * CB;  // s + h
    bool use_copy = ws_size >= COPY_BYTES + small_floats * 4 + 256;

    if (use_copy) {
        unsigned short* cp = (unsigned short*)d_ws;                 // 128 MiB
        float* s = (float*)((char*)d_ws + COPY_BYTES);              // 64 KiB
        float* h = s + (size_t)BB * CC;                             // 16 KiB
        se_pool_copy<<<NROW, 256, 0, stream>>>(in, s, cp);
        se_h<<<CB, 256, 0, stream>>>(s, w1, b1, h);
        se_bn<<<1, CB, 0, stream>>>(h, gamma, beta);
        se_mul_bf<<<NROW, 256, 0, stream>>>(cp, h, w2, b2, out);
    } else {
        float* s = (float*)d_ws;
        float* h = s + (size_t)BB * CC;
        se_pool<<<NROW, 256, 0, stream>>>(in, s);
        se_h<<<CB, 256, 0, stream>>>(s, w1, b1, h);
        se_bn<<<1, CB, 0, stream>>>(h, gamma, beta);
        se_mul<<<NROW, 256, 0, stream>>>(in, h, w2, b2, out);
    }
}

// Round 6
// 131.234 us; speedup vs baseline: 1.2902x; 1.2902x over previous
//
#include <hip/hip_runtime.h>
#include <math.h>

#define CC 512
#define CB 128
#define BB 32
#define HW 4096
#define NROW (BB * CC)                       // 16384 rows of 4096 floats
#define COPY_BYTES ((size_t)NROW * HW * 2)   // 128 MiB bf16 shadow copy

typedef float f32x4 __attribute__((ext_vector_type(4)));
typedef unsigned short u16x4 __attribute__((ext_vector_type(4)));

static __device__ __forceinline__ unsigned short f2bf(float x) {
    unsigned u = __float_as_uint(x);
    unsigned r = (u + 0x7fffu + ((u >> 16) & 1u)) >> 16;   // RNE
    return (unsigned short)r;
}
static __device__ __forceinline__ float bf2f(unsigned short b) {
    return __uint_as_float(((unsigned)b) << 16);
}

// ---- kernel 1: pool + write bf16 shadow copy ----
// NT loads on the cold input; normal stores for the copy (we want IT in L3).
__global__ __launch_bounds__(256) void se_pool_copy(const float* __restrict__ in,
                                                    float* __restrict__ s,
                                                    unsigned short* __restrict__ cp) {
    int bc = blockIdx.x;
    const f32x4* row = (const f32x4*)(in + (size_t)bc * HW);
    u16x4* crow = (u16x4*)(cp + (size_t)bc * HW);
    int t = threadIdx.x;
    float acc = 0.f;
#pragma unroll
    for (int i = 0; i < 4; ++i) {
        f32x4 v = __builtin_nontemporal_load(&row[t + i * 256]);
        acc += v.x + v.y + v.z + v.w;
        u16x4 c;
        c.x = f2bf(v.x); c.y = f2bf(v.y); c.z = f2bf(v.z); c.w = f2bf(v.w);
        crow[t + i * 256] = c;   // 8B/lane, lanes contiguous -> coalesced
    }
#pragma unroll
    for (int off = 32; off >= 1; off >>= 1)
        acc += __shfl_xor(acc, off, 64);
    __shared__ float red[4];
    if ((t & 63) == 0) red[t >> 6] = acc;
    __syncthreads();
    if (t == 0) s[bc] = (red[0] + red[1] + red[2] + red[3]) * (1.0f / HW);
}

// ---- kernel 2: h[b][k] = relu(s[b,:] . w1[k,:] + b1[k]) ; one block per k ----
__global__ __launch_bounds__(256) void se_h(const float* __restrict__ s,
                                            const float* __restrict__ w1,
                                            const float* __restrict__ b1,
                                            float* __restrict__ h) {
    int k = blockIdx.x;
    __shared__ float wrow[CC];
    int t = threadIdx.x;
    wrow[t]       = w1[k * CC + t];
    wrow[t + 256] = w1[k * CC + t + 256];
    __syncthreads();
    int b = t >> 3;
    int p = t & 7;
    const float* srow = s + b * CC + p * 64;
    const float* wp   = wrow + p * 64;
    float acc = 0.f;
#pragma unroll
    for (int j = 0; j < 64; ++j) acc += srow[j] * wp[j];
    acc += __shfl_xor(acc, 1, 64);
    acc += __shfl_xor(acc, 2, 64);
    acc += __shfl_xor(acc, 4, 64);
    if (p == 0) {
        float v = acc + b1[k];
        h[b * CB + k] = v > 0.f ? v : 0.f;
    }
}

// ---- kernel 3: batchnorm over batch dim (training-mode biased var), in place ----
__global__ __launch_bounds__(128) void se_bn(float* __restrict__ h,
                                             const float* __restrict__ gamma,
                                             const float* __restrict__ beta) {
    int k = threadIdx.x;
    float sum = 0.f, sumsq = 0.f;
#pragma unroll
    for (int b = 0; b < BB; ++b) {
        float v = h[b * CB + k];
        sum += v;
        sumsq += v * v;
    }
    float mu  = sum * (1.0f / BB);
    float var = sumsq * (1.0f / BB) - mu * mu;
    float sc  = gamma[k] * rsqrtf(var + 1e-5f);
    float sh  = beta[k] - mu * sc;
#pragma unroll
    for (int b = 0; b < BB; ++b)
        h[b * CB + k] = h[b * CB + k] * sc + sh;
}

// ---- kernel 4: excite from the bf16 copy; fully coalesced ----
// thread t owns 16B output slots t+i*256: load u16x4 (8B, contiguous),
// NT-store one f32x4 at the SAME slot (contiguous).
__global__ __launch_bounds__(256) void se_mul_bf(const unsigned short* __restrict__ cp,
                                                 const float* __restrict__ hn,
                                                 const float* __restrict__ w2,
                                                 const float* __restrict__ b2,
                                                 float* __restrict__ out) {
    int bc = (NROW - 1) - blockIdx.x;   // recency-aligned: copy tail first
    int b = bc >> 9;
    int c = bc & 511;
    const f32x4* hv = (const f32x4*)(hn + b * CB);
    const f32x4* wv = (const f32x4*)(w2 + c * CB);
    float acc = 0.f;
#pragma unroll
    for (int i = 0; i < 32; ++i) {
        f32x4 a = hv[i];
        f32x4 w = wv[i];
        acc += a.x * w.x + a.y * w.y + a.z * w.z + a.w * w.w;
    }
    float g = 1.0f / (1.0f + expf(-(acc + b2[c])));

    const u16x4* cv = (const u16x4*)(cp + (size_t)bc * HW);
    f32x4* ov       = (f32x4*)(out + (size_t)bc * HW);
    int t = threadIdx.x;
#pragma unroll
    for (int i = 0; i < 4; ++i) {
        u16x4 u = cv[t + i * 256];
        f32x4 v;
        v.x = bf2f(u.x) * g;
        v.y = bf2f(u.y) * g;
        v.z = bf2f(u.z) * g;
        v.w = bf2f(u.w) * g;
        __builtin_nontemporal_store(v, &ov[t + i * 256]);
    }
}

// ---- fallback path (ws too small): R3 versions ----
__global__ __launch_bounds__(256) void se_pool(const float* __restrict__ in,
                                               float* __restrict__ s) {
    int bc = blockIdx.x;
    const f32x4* row = (const f32x4*)(in + (size_t)bc * HW);
    int t = threadIdx.x;
    float acc = 0.f;
#pragma unroll
    for (int i = 0; i < 4; ++i) {
        f32x4 v = row[t + i * 256];
        acc += v.x + v.y + v.z + v.w;
    }
#pragma unroll
    for (int off = 32; off >= 1; off >>= 1)
        acc += __shfl_xor(acc, off, 64);
    __shared__ float red[4];
    if ((t & 63) == 0) red[t >> 6] = acc;
    __syncthreads();
    if (t == 0) s[bc] = (red[0] + red[1] + red[2] + red[3]) * (1.0f / HW);
}

__global__ __launch_bounds__(256) void se_mul(const float* __restrict__ in,
                                              const float* __restrict__ hn,
                                              const float* __restrict__ w2,
                                              const float* __restrict__ b2,
                                              float* __restrict__ out) {
    int bc = (NROW - 1) - blockIdx.x;
    int b = bc >> 9;
    int c = bc & 511;
    const f32x4* hv = (const f32x4*)(hn + b * CB);
    const f32x4* wv = (const f32x4*)(w2 + c * CB);
    float acc = 0.f;
#pragma unroll
    for (int i = 0; i < 32; ++i) {
        f32x4 a = hv[i];
        f32x4 w = wv[i];
        acc += a.x * w.x + a.y * w.y + a.z * w.z + a.w * w.w;
    }
    float g = 1.0f / (1.0f + expf(-(acc + b2[c])));

    const f32x4* iv = (const f32x4*)(in + (size_t)bc * HW);
    f32x4* ov       = (f32x4*)(out + (size_t)bc * HW);
    int t = threadIdx.x;
#pragma unroll
    for (int i = 0; i < 4; ++i) {
        f32x4 v = iv[t + i * 256];
        v.x *= g; v.y *= g; v.z *= g; v.w *= g;
        __builtin_nontemporal_store(v, &ov[t + i * 256]);
    }
}

extern "C" void kernel_launch(void* const* d_in, const int* in_sizes, int n_in,
                              void* d_out, int out_size, void* d_ws, size_t ws_size,
                              hipStream_t stream) {
    const float* in    = (const float*)d_in[0];
    const float* w1    = (const float*)d_in[1];
    const float* b1    = (const float*)d_in[2];
    const float* gamma = (const float*)d_in[3];
    const float* beta  = (const float*)d_in[4];
    const float* w2    = (const float*)d_in[5];
    const float* b2    = (const float*)d_in[6];
    float* out = (float*)d_out;

    const size_t small_floats = (size_t)BB * CC + (size_t)BB * CB;  // s + h
    bool use_copy = ws_size >= COPY_BYTES + small_floats * 4 + 256;

    if (use_copy) {
        unsigned short* cp = (unsigned short*)d_ws;                 // 128 MiB
        float* s = (float*)((char*)d_ws + COPY_BYTES);
        float* h = s + (size_t)BB * CC;
        se_pool_copy<<<NROW, 256, 0, stream>>>(in, s, cp);
        se_h<<<CB, 256, 0, stream>>>(s, w1, b1, h);
        se_bn<<<1, CB, 0, stream>>>(h, gamma, beta);
        se_mul_bf<<<NROW, 256, 0, stream>>>(cp, h, w2, b2, out);
    } else {
        float* s = (float*)d_ws;
        float* h = s + (size_t)BB * CC;
        se_pool<<<NROW, 256, 0, stream>>>(in, s);
        se_h<<<CB, 256, 0, stream>>>(s, w1, b1, h);
        se_bn<<<1, CB, 0, stream>>>(h, gamma, beta);
        se_mul<<<NROW, 256, 0, stream>>>(in, h, w2, b2, out);
    }
}